// Round 2
// baseline (11467.268 us; speedup 1.0000x reference)
//
#include <hip/hip_runtime.h>
#include <math.h>

#define N_NODES 50000
#define N_EDGES 500000
#define H 128
#define NL 3
#define TE 64
#define TN 64
#define KC 32
#define SCAN_B 256
#define NCHUNK ((N_NODES + SCAN_B - 1) / SCAN_B)

// ---------------- counting sort of edges by dst ----------------

__global__ void k_deg_i(const int* __restrict__ dst, int* __restrict__ degC) {
  int e = blockIdx.x * blockDim.x + threadIdx.x;
  if (e < N_EDGES) atomicAdd(&degC[dst[e]], 1);
}

__global__ void k_inv(const int* __restrict__ degC, float* __restrict__ invd) {
  int i = blockIdx.x * blockDim.x + threadIdx.x;
  if (i < N_NODES) invd[i] = 1.0f / fmaxf((float)degC[i], 1.0f);
}

__global__ void k_scan1(const int* __restrict__ degC, int* __restrict__ cursor,
                        int* __restrict__ chunkSum) {
  __shared__ int s[SCAN_B];
  int t = threadIdx.x, i = blockIdx.x * SCAN_B + t;
  int v = (i < N_NODES) ? degC[i] : 0;
  s[t] = v;
  __syncthreads();
  for (int o = 1; o < SCAN_B; o <<= 1) {
    int u = (t >= o) ? s[t - o] : 0;
    __syncthreads();
    s[t] += u;
    __syncthreads();
  }
  if (i < N_NODES) cursor[i] = s[t] - v;  // exclusive within chunk
  if (t == SCAN_B - 1) chunkSum[blockIdx.x] = s[t];
}

__global__ void k_scan2(int* __restrict__ chunkSum) {
  __shared__ int s[SCAN_B];
  int t = threadIdx.x;
  int v = (t < NCHUNK) ? chunkSum[t] : 0;
  s[t] = v;
  __syncthreads();
  for (int o = 1; o < SCAN_B; o <<= 1) {
    int u = (t >= o) ? s[t - o] : 0;
    __syncthreads();
    s[t] += u;
    __syncthreads();
  }
  if (t < NCHUNK) chunkSum[t] = s[t] - v;  // exclusive chunk offsets
}

__global__ void k_scan3(int* __restrict__ cursor, const int* __restrict__ chunkSum) {
  int i = blockIdx.x * SCAN_B + threadIdx.x;
  if (i < N_NODES) cursor[i] += chunkSum[blockIdx.x];
}

__global__ void k_scatter_sort(const int* __restrict__ dst, int* __restrict__ cursor,
                               int* __restrict__ sorted) {
  int e = blockIdx.x * blockDim.x + threadIdx.x;
  if (e < N_EDGES) {
    int p = atomicAdd(&cursor[dst[e]], 1);
    sorted[p] = e;
  }
}

// ---------------- fused edge kernel (dst-sorted tiles) ----------------
// inner microkernel: C[64 edges][128 feats] += A_chunk @ B_chunk
// thread (eg=tid>>5, fg=tid&31) owns rows eg*8..+7, cols fg*4..+3
#define GEMM_INNER(SRC_A, ASTRIDE, AOFF, ACCV)                                 \
  _Pragma("unroll")                                                            \
  for (int k = 0; k < KC; k += 4) {                                            \
    float4 b0 = *(float4*)&sB[(k + 0) * 128 + fg * 4];                         \
    float4 b1 = *(float4*)&sB[(k + 1) * 128 + fg * 4];                         \
    float4 b2 = *(float4*)&sB[(k + 2) * 128 + fg * 4];                         \
    float4 b3 = *(float4*)&sB[(k + 3) * 128 + fg * 4];                         \
    const float *bp0 = &b0.x, *bp1 = &b1.x, *bp2 = &b2.x, *bp3 = &b3.x;        \
    _Pragma("unroll")                                                          \
    for (int e = 0; e < 8; ++e) {                                              \
      float4 a = *(float4*)&SRC_A[(eg * 8 + e) * ASTRIDE + (AOFF) + k];        \
      _Pragma("unroll")                                                        \
      for (int f = 0; f < 4; ++f)                                              \
        ACCV[e][f] += a.x * bp0[f] + a.y * bp1[f] + a.z * bp2[f] + a.w * bp3[f]; \
    }                                                                          \
  }

__launch_bounds__(256, 2)
__global__ void k_edge(const float* __restrict__ x,
                       const float* __restrict__ pos,
                       const float* __restrict__ eattr,
                       const int* __restrict__ srcI,
                       const int* __restrict__ dstI,
                       const int* __restrict__ sorted,
                       const float* __restrict__ mW1, const float* __restrict__ mb1,
                       const float* __restrict__ mW2, const float* __restrict__ mb2,
                       const float* __restrict__ aW1, const float* __restrict__ ab1,
                       const float* __restrict__ aW2, const float* __restrict__ ab2,
                       float* __restrict__ intra,
                       float* __restrict__ pdelta,
                       int do_intra)
{
  __shared__ float sA[TE * KC];     // 8 KB staging (gathered input chunk)
  __shared__ float sB[KC * 128];    // 16 KB staging (weight chunk)
  __shared__ float sHM[TE * 128];   // 32 KB: h1, then m
  __shared__ int sEid[TE];
  __shared__ int sSrc[TE];
  __shared__ int sDst[TE];
  __shared__ float sW[TE];
  __shared__ float sPE[TE * 3];

  const int tid = threadIdx.x;
  const int e0 = blockIdx.x * TE;
  const int nv = min(N_EDGES - e0, TE);
  if (tid < TE) {
    int idx = min(e0 + tid, N_EDGES - 1);
    int eid = sorted[idx];
    sEid[tid] = eid;
    sSrc[tid] = srcI[eid];
    sDst[tid] = dstI[eid];
  }
  __syncthreads();

  const int fg = tid & 31;
  const int eg = tid >> 5;

  float acc[8][4];
#pragma unroll
  for (int e = 0; e < 8; ++e)
#pragma unroll
    for (int f = 0; f < 4; ++f) acc[e][f] = 0.0f;

  // ---- GEMM1: concat(x[dst], x[src], eattr) [TE,384] @ mW1 [384,128] ----
  for (int c = 0; c < 384 / KC; ++c) {
#pragma unroll
    for (int i = 0; i < (TE * KC / 4) / 256; ++i) {
      int flat = tid + i * 256;
      int e = flat / (KC / 4);
      int q = flat % (KC / 4);
      int col = c * KC + q * 4;
      const float* rp;
      if (col < H)            rp = x + (size_t)sDst[e] * H + col;
      else if (col < 2 * H)   rp = x + (size_t)sSrc[e] * H + (col - H);
      else                    rp = eattr + (size_t)sEid[e] * H + (col - 2 * H);
      *(float4*)&sA[e * KC + q * 4] = *(const float4*)rp;
    }
#pragma unroll
    for (int i = 0; i < (KC * 128 / 4) / 256; ++i) {
      int flat = tid + i * 256;
      int r = flat / 32, cq = flat % 32;
      *(float4*)&sB[r * 128 + cq * 4] =
          *(const float4*)&mW1[(size_t)(c * KC + r) * 128 + cq * 4];
    }
    __syncthreads();
    GEMM_INNER(sA, KC, 0, acc)
    __syncthreads();
  }

  // h1 = relu(acc + mb1) -> sHM
  {
    float4 bb = *(const float4*)&mb1[fg * 4];
    const float* bp = &bb.x;
#pragma unroll
    for (int e = 0; e < 8; ++e)
#pragma unroll
      for (int f = 0; f < 4; ++f) {
        sHM[(eg * 8 + e) * 128 + fg * 4 + f] = fmaxf(acc[e][f] + bp[f], 0.0f);
        acc[e][f] = 0.0f;
      }
  }
  __syncthreads();

  // ---- GEMM2: h1 [TE,128] @ mW2 [128,128] ----
  for (int c = 0; c < 128 / KC; ++c) {
#pragma unroll
    for (int i = 0; i < (KC * 128 / 4) / 256; ++i) {
      int flat = tid + i * 256;
      int r = flat / 32, cq = flat % 32;
      *(float4*)&sB[r * 128 + cq * 4] =
          *(const float4*)&mW2[(size_t)(c * KC + r) * 128 + cq * 4];
    }
    __syncthreads();
    GEMM_INNER(sHM, 128, c * KC, acc)
    __syncthreads();
  }

  // m = acc + mb2 -> sHM (overwrite h1; all GEMM2 reads are done)
  {
    float4 bb = *(const float4*)&mb2[fg * 4];
    const float* bp = &bb.x;
#pragma unroll
    for (int e = 0; e < 8; ++e)
#pragma unroll
      for (int f = 0; f < 4; ++f)
        sHM[(eg * 8 + e) * 128 + fg * 4 + f] = acc[e][f] + bp[f];
  }

  // ---- acc MLP: w = relu(m @ aW1 + ab1) @ aW2 + ab2 ----
  float wacc[8];
#pragma unroll
  for (int e = 0; e < 8; ++e) wacc[e] = 0.0f;

  for (int half = 0; half < 2; ++half) {
#pragma unroll
    for (int e = 0; e < 8; ++e)
#pragma unroll
      for (int f = 0; f < 4; ++f) acc[e][f] = 0.0f;
    for (int c = 0; c < 128 / KC; ++c) {
#pragma unroll
      for (int i = 0; i < (KC * 128 / 4) / 256; ++i) {
        int flat = tid + i * 256;
        int r = flat / 32, cq = flat % 32;
        *(float4*)&sB[r * 128 + cq * 4] =
            *(const float4*)&aW1[(size_t)(c * KC + r) * 256 + half * 128 + cq * 4];
      }
      __syncthreads();
      GEMM_INNER(sHM, 128, c * KC, acc)
      __syncthreads();
    }
    float4 bb = *(const float4*)&ab1[half * 128 + fg * 4];
    float4 w2 = *(const float4*)&aW2[half * 128 + fg * 4];
    const float* bp = &bb.x;
    const float* wp = &w2.x;
#pragma unroll
    for (int e = 0; e < 8; ++e)
#pragma unroll
      for (int f = 0; f < 4; ++f)
        wacc[e] += fmaxf(acc[e][f] + bp[f], 0.0f) * wp[f];
  }

#pragma unroll
  for (int m = 16; m >= 1; m >>= 1)
#pragma unroll
    for (int e = 0; e < 8; ++e)
      wacc[e] += __shfl_xor(wacc[e], m, 64);
  if (fg == 0) {
#pragma unroll
    for (int e = 0; e < 8; ++e) sW[eg * 8 + e] = wacc[e] + ab2[0];
  }
  __syncthreads();

  // ---- per-edge acc_e into LDS ----
  if (tid < nv) {
    int s = sSrc[tid], d = sDst[tid];
    float rx = pos[s * 3 + 0] - pos[d * 3 + 0];
    float ry = pos[s * 3 + 1] - pos[d * 3 + 1];
    float rz = pos[s * 3 + 2] - pos[d * 3 + 2];
    float dist = sqrtf(rx * rx + ry * ry + rz * rz);
    float cf = sW[tid] / dist;
    sPE[tid * 3 + 0] = cf * rx;
    sPE[tid * 3 + 1] = cf * ry;
    sPE[tid * 3 + 2] = cf * rz;
  }
  __syncthreads();

  // ---- segment-reduced scatter: pdelta (dst-sorted => runs collapse) ----
  if (tid < 3) {
    float run = 0.0f;
    int cur = -2;
    for (int e = 0; e < TE; ++e) {
      int d = (e < nv) ? sDst[e] : -1;
      if (d != cur) {
        if (cur >= 0 && run != 0.0f) atomicAdd(&pdelta[cur * 3 + tid], run);
        run = 0.0f;
        cur = d;
      }
      if (d >= 0) run += sPE[e * 3 + tid];
    }
    if (cur >= 0 && run != 0.0f) atomicAdd(&pdelta[cur * 3 + tid], run);
  }

  // ---- segment-reduced scatter: intra ----
  if (do_intra) {
    int f = tid & 127;
    int half = tid >> 7;
    int eBeg = half * 32, eEnd = eBeg + 32;
    float run = 0.0f;
    int cur = -2;
    for (int e = eBeg; e < eEnd; ++e) {
      int d = (e < nv) ? sDst[e] : -1;
      if (d != cur) {
        if (cur >= 0 && run != 0.0f) atomicAdd(&intra[(size_t)cur * H + f], run);
        run = 0.0f;
        cur = d;
      }
      if (d >= 0) run += sHM[e * 128 + f];
    }
    if (cur >= 0 && run != 0.0f) atomicAdd(&intra[(size_t)cur * H + f], run);
  }
}

// ---------------- node kernel (unchanged) ----------------

__launch_bounds__(256, 2)
__global__ void k_node(const float* __restrict__ x,
                       const float* __restrict__ intra,
                       const float* __restrict__ invd,
                       const float* __restrict__ nW1, const float* __restrict__ nb1,
                       const float* __restrict__ nW2, const float* __restrict__ nb2,
                       const float* __restrict__ pos_in,
                       const float* __restrict__ pdelta,
                       float* __restrict__ x_out,
                       float* __restrict__ pos_out,
                       int compute_x)
{
  __shared__ float sA[TN * KC];
  __shared__ float sB[KC * 128];
  __shared__ float sH[TN * 128];
  const int tid = threadIdx.x;
  const int n0 = blockIdx.x * TN;

  if (tid < 192) {
    int n = n0 + tid / 3, cc = tid % 3;
    if (n < N_NODES)
      pos_out[n * 3 + cc] = pos_in[n * 3 + cc] + pdelta[n * 3 + cc] * invd[n];
  }
  if (!compute_x) return;

  const int fg = tid & 31, eg = tid >> 5;
  float xacc[8][4], acc[8][4];
#pragma unroll
  for (int e = 0; e < 8; ++e)
#pragma unroll
    for (int f = 0; f < 4; ++f) xacc[e][f] = 0.0f;

  for (int half = 0; half < 2; ++half) {
#pragma unroll
    for (int e = 0; e < 8; ++e)
#pragma unroll
      for (int f = 0; f < 4; ++f) acc[e][f] = 0.0f;
    for (int c = 0; c < 256 / KC; ++c) {
#pragma unroll
      for (int i = 0; i < (TN * KC / 4) / 256; ++i) {
        int flat = tid + i * 256;
        int e = flat / (KC / 4), q = flat % (KC / 4);
        int col = c * KC + q * 4;
        int n = min(n0 + e, N_NODES - 1);
        float4 v;
        if (col < H) {
          v = *(const float4*)&x[(size_t)n * H + col];
        } else {
          v = *(const float4*)&intra[(size_t)n * H + (col - H)];
          float iv = invd[n];
          v.x *= iv; v.y *= iv; v.z *= iv; v.w *= iv;
        }
        *(float4*)&sA[e * KC + q * 4] = v;
      }
#pragma unroll
      for (int i = 0; i < (KC * 128 / 4) / 256; ++i) {
        int flat = tid + i * 256;
        int r = flat / 32, cq = flat % 32;
        *(float4*)&sB[r * 128 + cq * 4] =
            *(const float4*)&nW1[(size_t)(c * KC + r) * 256 + half * 128 + cq * 4];
      }
      __syncthreads();
      GEMM_INNER(sA, KC, 0, acc)
      __syncthreads();
    }
    {
      float4 bb = *(const float4*)&nb1[half * 128 + fg * 4];
      const float* bp = &bb.x;
#pragma unroll
      for (int e = 0; e < 8; ++e)
#pragma unroll
        for (int f = 0; f < 4; ++f)
          sH[(eg * 8 + e) * 128 + fg * 4 + f] = fmaxf(acc[e][f] + bp[f], 0.0f);
    }
    for (int c = 0; c < 128 / KC; ++c) {
#pragma unroll
      for (int i = 0; i < (KC * 128 / 4) / 256; ++i) {
        int flat = tid + i * 256;
        int r = flat / 32, cq = flat % 32;
        *(float4*)&sB[r * 128 + cq * 4] =
            *(const float4*)&nW2[(size_t)(half * 128 + c * KC + r) * 128 + cq * 4];
      }
      __syncthreads();
      GEMM_INNER(sH, 128, c * KC, xacc)
      __syncthreads();
    }
  }
  {
    float4 bb = *(const float4*)&nb2[fg * 4];
    const float* bp = &bb.x;
#pragma unroll
    for (int e = 0; e < 8; ++e) {
      int n = n0 + eg * 8 + e;
      if (n < N_NODES) {
        float4 o;
        o.x = xacc[e][0] + bp[0];
        o.y = xacc[e][1] + bp[1];
        o.z = xacc[e][2] + bp[2];
        o.w = xacc[e][3] + bp[3];
        *(float4*)&x_out[(size_t)n * H + fg * 4] = o;
      }
    }
  }
}

extern "C" void kernel_launch(void* const* d_in, const int* in_sizes, int n_in,
                              void* d_out, int out_size, void* d_ws, size_t ws_size,
                              hipStream_t stream) {
  const float* x0    = (const float*)d_in[0];
  const int*   eidx  = (const int*)d_in[1];
  const float* eattr = (const float*)d_in[2];
  const float* pos0  = (const float*)d_in[3];
  const float* mW1 = (const float*)d_in[4];
  const float* mb1 = (const float*)d_in[5];
  const float* mW2 = (const float*)d_in[6];
  const float* mb2 = (const float*)d_in[7];
  const float* aW1 = (const float*)d_in[8];
  const float* ab1 = (const float*)d_in[9];
  const float* aW2 = (const float*)d_in[10];
  const float* ab2 = (const float*)d_in[11];
  const float* nW1 = (const float*)d_in[12];
  const float* nb1 = (const float*)d_in[13];
  const float* nW2 = (const float*)d_in[14];
  const float* nb2 = (const float*)d_in[15];
  const int* srcI = eidx;
  const int* dstI = eidx + N_EDGES;

  char* wsb = (char*)d_ws;
  int*   degC    = (int*)wsb;                     wsb += (size_t)N_NODES * 4;
  int*   cursor  = (int*)wsb;                     wsb += (size_t)N_NODES * 4;
  int*   chunkS  = (int*)wsb;                     wsb += 256 * 4;
  int*   sorted  = (int*)wsb;                     wsb += (size_t)N_EDGES * 4;
  float* invd    = (float*)wsb;                   wsb += (size_t)N_NODES * 4;
  float* pdelta  = (float*)wsb;                   wsb += (size_t)3 * N_NODES * 4;
  float* pos_a   = (float*)wsb;                   wsb += (size_t)3 * N_NODES * 4;
  float* pos_b   = (float*)wsb;                   wsb += (size_t)3 * N_NODES * 4;
  float* intra   = (float*)wsb;                   wsb += (size_t)N_NODES * H * 4;
  float* x_a     = (float*)wsb;                   wsb += (size_t)N_NODES * H * 4;
  float* x_b     = (float*)wsb;                   wsb += (size_t)N_NODES * H * 4;

  // counting sort of edges by dst (runs every launch; ws is re-poisoned)
  hipMemsetAsync(degC, 0, N_NODES * sizeof(int), stream);
  k_deg_i<<<(N_EDGES + 255) / 256, 256, 0, stream>>>(dstI, degC);
  k_inv<<<(N_NODES + 255) / 256, 256, 0, stream>>>(degC, invd);
  k_scan1<<<NCHUNK, SCAN_B, 0, stream>>>(degC, cursor, chunkS);
  k_scan2<<<1, SCAN_B, 0, stream>>>(chunkS);
  k_scan3<<<NCHUNK, SCAN_B, 0, stream>>>(cursor, chunkS);
  k_scatter_sort<<<(N_EDGES + 255) / 256, 256, 0, stream>>>(dstI, cursor, sorted);

  const float* xc = x0;
  const float* pc = pos0;
  float* pos_out_final = (float*)d_out;

  for (int l = 0; l < NL; ++l) {
    int last = (l == NL - 1);
    hipMemsetAsync(pdelta, 0, 3 * N_NODES * sizeof(float), stream);
    if (!last)
      hipMemsetAsync(intra, 0, (size_t)N_NODES * H * sizeof(float), stream);

    k_edge<<<(N_EDGES + TE - 1) / TE, 256, 0, stream>>>(
        xc, pc, eattr, srcI, dstI, sorted,
        mW1 + (size_t)l * 384 * 128, mb1 + (size_t)l * 128,
        mW2 + (size_t)l * 128 * 128, mb2 + (size_t)l * 128,
        aW1 + (size_t)l * 128 * 256, ab1 + (size_t)l * 256,
        aW2 + (size_t)l * 256, ab2 + l,
        intra, pdelta, last ? 0 : 1);

    float* pn = last ? pos_out_final : (l == 0 ? pos_a : pos_b);
    float* xn = (l == 0) ? x_a : x_b;
    k_node<<<(N_NODES + TN - 1) / TN, 256, 0, stream>>>(
        xc, intra, invd,
        nW1 + (size_t)l * 256 * 256, nb1 + (size_t)l * 256,
        nW2 + (size_t)l * 256 * 128, nb2 + (size_t)l * 128,
        pc, pdelta, xn, pn, last ? 0 : 1);

    xc = xn;
    pc = pn;
  }
}

// Round 3
// 11054.732 us; speedup vs baseline: 1.0373x; 1.0373x over previous
//
#include <hip/hip_runtime.h>
#include <math.h>

#define N_NODES 50000
#define N_EDGES 500000
#define H 128
#define NL 3
#define TE 64
#define TN 64
#define KC 32
#define SCAN_B 256
#define NCHUNK ((N_NODES + SCAN_B - 1) / SCAN_B)

// ---------------- counting sort of edges by dst ----------------

__global__ void k_deg_i(const int* __restrict__ dst, int* __restrict__ degC) {
  int e = blockIdx.x * blockDim.x + threadIdx.x;
  if (e < N_EDGES) atomicAdd(&degC[dst[e]], 1);
}

__global__ void k_inv(const int* __restrict__ degC, float* __restrict__ invd) {
  int i = blockIdx.x * blockDim.x + threadIdx.x;
  if (i < N_NODES) invd[i] = 1.0f / fmaxf((float)degC[i], 1.0f);
}

__global__ void k_scan1(const int* __restrict__ degC, int* __restrict__ cursor,
                        int* __restrict__ chunkSum) {
  __shared__ int s[SCAN_B];
  int t = threadIdx.x, i = blockIdx.x * SCAN_B + t;
  int v = (i < N_NODES) ? degC[i] : 0;
  s[t] = v;
  __syncthreads();
  for (int o = 1; o < SCAN_B; o <<= 1) {
    int u = (t >= o) ? s[t - o] : 0;
    __syncthreads();
    s[t] += u;
    __syncthreads();
  }
  if (i < N_NODES) cursor[i] = s[t] - v;
  if (t == SCAN_B - 1) chunkSum[blockIdx.x] = s[t];
}

__global__ void k_scan2(int* __restrict__ chunkSum) {
  __shared__ int s[SCAN_B];
  int t = threadIdx.x;
  int v = (t < NCHUNK) ? chunkSum[t] : 0;
  s[t] = v;
  __syncthreads();
  for (int o = 1; o < SCAN_B; o <<= 1) {
    int u = (t >= o) ? s[t - o] : 0;
    __syncthreads();
    s[t] += u;
    __syncthreads();
  }
  if (t < NCHUNK) chunkSum[t] = s[t] - v;
}

__global__ void k_scan3(int* __restrict__ cursor, const int* __restrict__ chunkSum) {
  int i = blockIdx.x * SCAN_B + threadIdx.x;
  if (i < N_NODES) cursor[i] += chunkSum[blockIdx.x];
}

__global__ void k_scatter_sort(const int* __restrict__ dst, int* __restrict__ cursor,
                               int* __restrict__ sorted) {
  int e = blockIdx.x * blockDim.x + threadIdx.x;
  if (e < N_EDGES) {
    int p = atomicAdd(&cursor[dst[e]], 1);
    sorted[p] = e;
  }
}

// ---------------- GEMM inner chunk: explicit components, no address-taken
// locals anywhere. thread (eg,fg) owns rows eg*8..+7, cols fg*4..+3.
#define GEMM_CHUNK(SRC_A, ASTRIDE, AOFF, ACCN)                                 \
  _Pragma("unroll")                                                            \
  for (int k = 0; k < KC; k += 4) {                                            \
    const float4 b0 = *(const float4*)&sB[(k + 0) * 128 + fg * 4];             \
    const float4 b1 = *(const float4*)&sB[(k + 1) * 128 + fg * 4];             \
    const float4 b2 = *(const float4*)&sB[(k + 2) * 128 + fg * 4];             \
    const float4 b3 = *(const float4*)&sB[(k + 3) * 128 + fg * 4];             \
    _Pragma("unroll")                                                          \
    for (int e = 0; e < 8; ++e) {                                              \
      const float4 a = *(const float4*)&SRC_A[(eg * 8 + e) * ASTRIDE + (AOFF) + k]; \
      ACCN[e].x += a.x * b0.x + a.y * b1.x + a.z * b2.x + a.w * b3.x;          \
      ACCN[e].y += a.x * b0.y + a.y * b1.y + a.z * b2.y + a.w * b3.y;          \
      ACCN[e].z += a.x * b0.z + a.y * b1.z + a.z * b2.z + a.w * b3.z;          \
      ACCN[e].w += a.x * b0.w + a.y * b1.w + a.z * b2.w + a.w * b3.w;          \
    }                                                                          \
  }

__launch_bounds__(256, 2)
__global__ void k_edge(const float* __restrict__ x,
                       const float* __restrict__ pos,
                       const float* __restrict__ eattr,
                       const int* __restrict__ srcI,
                       const int* __restrict__ dstI,
                       const int* __restrict__ sorted,
                       const float* __restrict__ mW1, const float* __restrict__ mb1,
                       const float* __restrict__ mW2, const float* __restrict__ mb2,
                       const float* __restrict__ aW1, const float* __restrict__ ab1,
                       const float* __restrict__ aW2, const float* __restrict__ ab2,
                       float* __restrict__ intra,
                       float* __restrict__ pdelta,
                       int do_intra)
{
  __shared__ float sA[TE * KC];
  __shared__ float sB[KC * 128];
  __shared__ float sHM[TE * 128];
  __shared__ int sEid[TE];
  __shared__ int sSrc[TE];
  __shared__ int sDst[TE];
  __shared__ float sW[TE];
  __shared__ float sPE[TE * 3];

  const int tid = threadIdx.x;
  const int e0 = blockIdx.x * TE;
  const int nv = min(N_EDGES - e0, TE);
  if (tid < TE) {
    int idx = min(e0 + tid, N_EDGES - 1);
    int eid = sorted[idx];
    sEid[tid] = eid;
    sSrc[tid] = srcI[eid];
    sDst[tid] = dstI[eid];
  }
  __syncthreads();

  const int fg = tid & 31;
  const int eg = tid >> 5;

  float4 acc[8];
#pragma unroll
  for (int e = 0; e < 8; ++e) acc[e] = make_float4(0.f, 0.f, 0.f, 0.f);

  // ---- GEMM1: concat(x[dst], x[src], eattr) [TE,384] @ mW1 [384,128] ----
  for (int c = 0; c < 384 / KC; ++c) {
#pragma unroll
    for (int i = 0; i < (TE * KC / 4) / 256; ++i) {
      int flat = tid + i * 256;
      int e = flat / (KC / 4);
      int q = flat % (KC / 4);
      int col = c * KC + q * 4;
      const float* rp;
      if (col < H)            rp = x + (size_t)sDst[e] * H + col;
      else if (col < 2 * H)   rp = x + (size_t)sSrc[e] * H + (col - H);
      else                    rp = eattr + (size_t)sEid[e] * H + (col - 2 * H);
      *(float4*)&sA[e * KC + q * 4] = *(const float4*)rp;
    }
#pragma unroll
    for (int i = 0; i < (KC * 128 / 4) / 256; ++i) {
      int flat = tid + i * 256;
      int r = flat / 32, cq = flat % 32;
      *(float4*)&sB[r * 128 + cq * 4] =
          *(const float4*)&mW1[(size_t)(c * KC + r) * 128 + cq * 4];
    }
    __syncthreads();
    GEMM_CHUNK(sA, KC, 0, acc)
    __syncthreads();
  }

  // h1 = relu(acc + mb1) -> sHM
  {
    const float4 bb = *(const float4*)&mb1[fg * 4];
#pragma unroll
    for (int e = 0; e < 8; ++e) {
      float* o = &sHM[(eg * 8 + e) * 128 + fg * 4];
      o[0] = fmaxf(acc[e].x + bb.x, 0.0f);
      o[1] = fmaxf(acc[e].y + bb.y, 0.0f);
      o[2] = fmaxf(acc[e].z + bb.z, 0.0f);
      o[3] = fmaxf(acc[e].w + bb.w, 0.0f);
      acc[e] = make_float4(0.f, 0.f, 0.f, 0.f);
    }
  }
  __syncthreads();

  // ---- GEMM2: h1 [TE,128] @ mW2 [128,128] ----
  for (int c = 0; c < 128 / KC; ++c) {
#pragma unroll
    for (int i = 0; i < (KC * 128 / 4) / 256; ++i) {
      int flat = tid + i * 256;
      int r = flat / 32, cq = flat % 32;
      *(float4*)&sB[r * 128 + cq * 4] =
          *(const float4*)&mW2[(size_t)(c * KC + r) * 128 + cq * 4];
    }
    __syncthreads();
    GEMM_CHUNK(sHM, 128, c * KC, acc)
    __syncthreads();
  }

  // m = acc + mb2 -> sHM
  {
    const float4 bb = *(const float4*)&mb2[fg * 4];
#pragma unroll
    for (int e = 0; e < 8; ++e) {
      float* o = &sHM[(eg * 8 + e) * 128 + fg * 4];
      o[0] = acc[e].x + bb.x;
      o[1] = acc[e].y + bb.y;
      o[2] = acc[e].z + bb.z;
      o[3] = acc[e].w + bb.w;
    }
  }

  // ---- acc MLP: w = relu(m @ aW1 + ab1) @ aW2 + ab2 ----
  float wacc[8];
#pragma unroll
  for (int e = 0; e < 8; ++e) wacc[e] = 0.0f;

  for (int half = 0; half < 2; ++half) {
#pragma unroll
    for (int e = 0; e < 8; ++e) acc[e] = make_float4(0.f, 0.f, 0.f, 0.f);
    for (int c = 0; c < 128 / KC; ++c) {
#pragma unroll
      for (int i = 0; i < (KC * 128 / 4) / 256; ++i) {
        int flat = tid + i * 256;
        int r = flat / 32, cq = flat % 32;
        *(float4*)&sB[r * 128 + cq * 4] =
            *(const float4*)&aW1[(size_t)(c * KC + r) * 256 + half * 128 + cq * 4];
      }
      __syncthreads();
      GEMM_CHUNK(sHM, 128, c * KC, acc)
      __syncthreads();
    }
    const float4 bb = *(const float4*)&ab1[half * 128 + fg * 4];
    const float4 w2 = *(const float4*)&aW2[half * 128 + fg * 4];
#pragma unroll
    for (int e = 0; e < 8; ++e) {
      wacc[e] += fmaxf(acc[e].x + bb.x, 0.0f) * w2.x
               + fmaxf(acc[e].y + bb.y, 0.0f) * w2.y
               + fmaxf(acc[e].z + bb.z, 0.0f) * w2.z
               + fmaxf(acc[e].w + bb.w, 0.0f) * w2.w;
    }
  }

#pragma unroll
  for (int m = 16; m >= 1; m >>= 1)
#pragma unroll
    for (int e = 0; e < 8; ++e)
      wacc[e] += __shfl_xor(wacc[e], m, 64);
  if (fg == 0) {
#pragma unroll
    for (int e = 0; e < 8; ++e) sW[eg * 8 + e] = wacc[e] + ab2[0];
  }
  __syncthreads();

  // ---- per-edge acc_e into LDS ----
  if (tid < nv) {
    int s = sSrc[tid], d = sDst[tid];
    float rx = pos[s * 3 + 0] - pos[d * 3 + 0];
    float ry = pos[s * 3 + 1] - pos[d * 3 + 1];
    float rz = pos[s * 3 + 2] - pos[d * 3 + 2];
    float dist = sqrtf(rx * rx + ry * ry + rz * rz);
    float cf = sW[tid] / dist;
    sPE[tid * 3 + 0] = cf * rx;
    sPE[tid * 3 + 1] = cf * ry;
    sPE[tid * 3 + 2] = cf * rz;
  }
  __syncthreads();

  // ---- segment-reduced scatter: pdelta ----
  if (tid < 3) {
    float run = 0.0f;
    int cur = -2;
    for (int e = 0; e < TE; ++e) {
      int d = (e < nv) ? sDst[e] : -1;
      if (d != cur) {
        if (cur >= 0 && run != 0.0f) atomicAdd(&pdelta[cur * 3 + tid], run);
        run = 0.0f;
        cur = d;
      }
      if (d >= 0) run += sPE[e * 3 + tid];
    }
    if (cur >= 0 && run != 0.0f) atomicAdd(&pdelta[cur * 3 + tid], run);
  }

  // ---- segment-reduced scatter: intra ----
  if (do_intra) {
    int f = tid & 127;
    int half = tid >> 7;
    int eBeg = half * 32, eEnd = eBeg + 32;
    float run = 0.0f;
    int cur = -2;
    for (int e = eBeg; e < eEnd; ++e) {
      int d = (e < nv) ? sDst[e] : -1;
      if (d != cur) {
        if (cur >= 0 && run != 0.0f) atomicAdd(&intra[(size_t)cur * H + f], run);
        run = 0.0f;
        cur = d;
      }
      if (d >= 0) run += sHM[e * 128 + f];
    }
    if (cur >= 0 && run != 0.0f) atomicAdd(&intra[(size_t)cur * H + f], run);
  }
}

// ---------------- node kernel ----------------

__launch_bounds__(256, 2)
__global__ void k_node(const float* __restrict__ x,
                       const float* __restrict__ intra,
                       const float* __restrict__ invd,
                       const float* __restrict__ nW1, const float* __restrict__ nb1,
                       const float* __restrict__ nW2, const float* __restrict__ nb2,
                       const float* __restrict__ pos_in,
                       const float* __restrict__ pdelta,
                       float* __restrict__ x_out,
                       float* __restrict__ pos_out,
                       int compute_x)
{
  __shared__ float sA[TN * KC];
  __shared__ float sB[KC * 128];
  __shared__ float sH[TN * 128];
  const int tid = threadIdx.x;
  const int n0 = blockIdx.x * TN;

  if (tid < 192) {
    int n = n0 + tid / 3, cc = tid % 3;
    if (n < N_NODES)
      pos_out[n * 3 + cc] = pos_in[n * 3 + cc] + pdelta[n * 3 + cc] * invd[n];
  }
  if (!compute_x) return;

  const int fg = tid & 31, eg = tid >> 5;
  float4 xacc[8], acc[8];
#pragma unroll
  for (int e = 0; e < 8; ++e) xacc[e] = make_float4(0.f, 0.f, 0.f, 0.f);

  for (int half = 0; half < 2; ++half) {
#pragma unroll
    for (int e = 0; e < 8; ++e) acc[e] = make_float4(0.f, 0.f, 0.f, 0.f);
    for (int c = 0; c < 256 / KC; ++c) {
#pragma unroll
      for (int i = 0; i < (TN * KC / 4) / 256; ++i) {
        int flat = tid + i * 256;
        int e = flat / (KC / 4), q = flat % (KC / 4);
        int col = c * KC + q * 4;
        int n = min(n0 + e, N_NODES - 1);
        float4 v;
        if (col < H) {
          v = *(const float4*)&x[(size_t)n * H + col];
        } else {
          v = *(const float4*)&intra[(size_t)n * H + (col - H)];
          float iv = invd[n];
          v.x *= iv; v.y *= iv; v.z *= iv; v.w *= iv;
        }
        *(float4*)&sA[e * KC + q * 4] = v;
      }
#pragma unroll
      for (int i = 0; i < (KC * 128 / 4) / 256; ++i) {
        int flat = tid + i * 256;
        int r = flat / 32, cq = flat % 32;
        *(float4*)&sB[r * 128 + cq * 4] =
            *(const float4*)&nW1[(size_t)(c * KC + r) * 256 + half * 128 + cq * 4];
      }
      __syncthreads();
      GEMM_CHUNK(sA, KC, 0, acc)
      __syncthreads();
    }
    {
      const float4 bb = *(const float4*)&nb1[half * 128 + fg * 4];
#pragma unroll
      for (int e = 0; e < 8; ++e) {
        float* o = &sH[(eg * 8 + e) * 128 + fg * 4];
        o[0] = fmaxf(acc[e].x + bb.x, 0.0f);
        o[1] = fmaxf(acc[e].y + bb.y, 0.0f);
        o[2] = fmaxf(acc[e].z + bb.z, 0.0f);
        o[3] = fmaxf(acc[e].w + bb.w, 0.0f);
      }
    }
    for (int c = 0; c < 128 / KC; ++c) {
#pragma unroll
      for (int i = 0; i < (KC * 128 / 4) / 256; ++i) {
        int flat = tid + i * 256;
        int r = flat / 32, cq = flat % 32;
        *(float4*)&sB[r * 128 + cq * 4] =
            *(const float4*)&nW2[(size_t)(half * 128 + c * KC + r) * 128 + cq * 4];
      }
      __syncthreads();
      GEMM_CHUNK(sH, 128, c * KC, xacc)
      __syncthreads();
    }
  }
  {
    const float4 bb = *(const float4*)&nb2[fg * 4];
#pragma unroll
    for (int e = 0; e < 8; ++e) {
      int n = n0 + eg * 8 + e;
      if (n < N_NODES) {
        float4 o;
        o.x = xacc[e].x + bb.x;
        o.y = xacc[e].y + bb.y;
        o.z = xacc[e].z + bb.z;
        o.w = xacc[e].w + bb.w;
        *(float4*)&x_out[(size_t)n * H + fg * 4] = o;
      }
    }
  }
}

extern "C" void kernel_launch(void* const* d_in, const int* in_sizes, int n_in,
                              void* d_out, int out_size, void* d_ws, size_t ws_size,
                              hipStream_t stream) {
  const float* x0    = (const float*)d_in[0];
  const int*   eidx  = (const int*)d_in[1];
  const float* eattr = (const float*)d_in[2];
  const float* pos0  = (const float*)d_in[3];
  const float* mW1 = (const float*)d_in[4];
  const float* mb1 = (const float*)d_in[5];
  const float* mW2 = (const float*)d_in[6];
  const float* mb2 = (const float*)d_in[7];
  const float* aW1 = (const float*)d_in[8];
  const float* ab1 = (const float*)d_in[9];
  const float* aW2 = (const float*)d_in[10];
  const float* ab2 = (const float*)d_in[11];
  const float* nW1 = (const float*)d_in[12];
  const float* nb1 = (const float*)d_in[13];
  const float* nW2 = (const float*)d_in[14];
  const float* nb2 = (const float*)d_in[15];
  const int* srcI = eidx;
  const int* dstI = eidx + N_EDGES;

  char* wsb = (char*)d_ws;
  int*   degC    = (int*)wsb;                     wsb += (size_t)N_NODES * 4;
  int*   cursor  = (int*)wsb;                     wsb += (size_t)N_NODES * 4;
  int*   chunkS  = (int*)wsb;                     wsb += 256 * 4;
  int*   sorted  = (int*)wsb;                     wsb += (size_t)N_EDGES * 4;
  float* invd    = (float*)wsb;                   wsb += (size_t)N_NODES * 4;
  float* pdelta  = (float*)wsb;                   wsb += (size_t)3 * N_NODES * 4;
  float* pos_a   = (float*)wsb;                   wsb += (size_t)3 * N_NODES * 4;
  float* pos_b   = (float*)wsb;                   wsb += (size_t)3 * N_NODES * 4;
  float* intra   = (float*)wsb;                   wsb += (size_t)N_NODES * H * 4;
  float* x_a     = (float*)wsb;                   wsb += (size_t)N_NODES * H * 4;
  float* x_b     = (float*)wsb;                   wsb += (size_t)N_NODES * H * 4;

  hipMemsetAsync(degC, 0, N_NODES * sizeof(int), stream);
  k_deg_i<<<(N_EDGES + 255) / 256, 256, 0, stream>>>(dstI, degC);
  k_inv<<<(N_NODES + 255) / 256, 256, 0, stream>>>(degC, invd);
  k_scan1<<<NCHUNK, SCAN_B, 0, stream>>>(degC, cursor, chunkS);
  k_scan2<<<1, SCAN_B, 0, stream>>>(chunkS);
  k_scan3<<<NCHUNK, SCAN_B, 0, stream>>>(cursor, chunkS);
  k_scatter_sort<<<(N_EDGES + 255) / 256, 256, 0, stream>>>(dstI, cursor, sorted);

  const float* xc = x0;
  const float* pc = pos0;
  float* pos_out_final = (float*)d_out;

  for (int l = 0; l < NL; ++l) {
    int last = (l == NL - 1);
    hipMemsetAsync(pdelta, 0, 3 * N_NODES * sizeof(float), stream);
    if (!last)
      hipMemsetAsync(intra, 0, (size_t)N_NODES * H * sizeof(float), stream);

    k_edge<<<(N_EDGES + TE - 1) / TE, 256, 0, stream>>>(
        xc, pc, eattr, srcI, dstI, sorted,
        mW1 + (size_t)l * 384 * 128, mb1 + (size_t)l * 128,
        mW2 + (size_t)l * 128 * 128, mb2 + (size_t)l * 128,
        aW1 + (size_t)l * 128 * 256, ab1 + (size_t)l * 256,
        aW2 + (size_t)l * 256, ab2 + l,
        intra, pdelta, last ? 0 : 1);

    float* pn = last ? pos_out_final : (l == 0 ? pos_a : pos_b);
    float* xn = (l == 0) ? x_a : x_b;
    k_node<<<(N_NODES + TN - 1) / TN, 256, 0, stream>>>(
        xc, intra, invd,
        nW1 + (size_t)l * 256 * 256, nb1 + (size_t)l * 256,
        nW2 + (size_t)l * 256 * 128, nb2 + (size_t)l * 128,
        pc, pdelta, xn, pn, last ? 0 : 1);

    xc = xn;
    pc = pn;
  }
}

// Round 4
// 1388.546 us; speedup vs baseline: 8.2585x; 7.9614x over previous
//
#include <hip/hip_runtime.h>
#include <hip/hip_bf16.h>
#include <math.h>

#define N_NODES 50000
#define N_EDGES 500000
#define H 128
#define NL 3
#define SCAN_B 256
#define NCHUNK ((N_NODES + SCAN_B - 1) / SCAN_B)

typedef short short8v __attribute__((ext_vector_type(8)));
typedef float f32x4 __attribute__((ext_vector_type(4)));
typedef unsigned short ushort8v __attribute__((ext_vector_type(8)));
typedef unsigned short ushort4v __attribute__((ext_vector_type(4)));

__device__ __forceinline__ unsigned short f2b(float f) {
  __hip_bfloat16 h = __float2bfloat16(f);
  return __builtin_bit_cast(unsigned short, h);
}
__device__ __forceinline__ float b2f(unsigned short s) {
  unsigned u = (unsigned)s << 16;
  return __builtin_bit_cast(float, u);
}

// ---------------- counting sort of edges by dst ----------------

__global__ void k_deg_i(const int* __restrict__ dst, int* __restrict__ degC) {
  int e = blockIdx.x * blockDim.x + threadIdx.x;
  if (e < N_EDGES) atomicAdd(&degC[dst[e]], 1);
}

__global__ void k_inv(const int* __restrict__ degC, float* __restrict__ invd) {
  int i = blockIdx.x * blockDim.x + threadIdx.x;
  if (i < N_NODES) invd[i] = 1.0f / fmaxf((float)degC[i], 1.0f);
}

__global__ void k_scan1(const int* __restrict__ degC, int* __restrict__ cursor,
                        int* __restrict__ chunkSum) {
  __shared__ int s[SCAN_B];
  int t = threadIdx.x, i = blockIdx.x * SCAN_B + t;
  int v = (i < N_NODES) ? degC[i] : 0;
  s[t] = v;
  __syncthreads();
  for (int o = 1; o < SCAN_B; o <<= 1) {
    int u = (t >= o) ? s[t - o] : 0;
    __syncthreads();
    s[t] += u;
    __syncthreads();
  }
  if (i < N_NODES) cursor[i] = s[t] - v;
  if (t == SCAN_B - 1) chunkSum[blockIdx.x] = s[t];
}

__global__ void k_scan2(int* __restrict__ chunkSum) {
  __shared__ int s[SCAN_B];
  int t = threadIdx.x;
  int v = (t < NCHUNK) ? chunkSum[t] : 0;
  s[t] = v;
  __syncthreads();
  for (int o = 1; o < SCAN_B; o <<= 1) {
    int u = (t >= o) ? s[t - o] : 0;
    __syncthreads();
    s[t] += u;
    __syncthreads();
  }
  if (t < NCHUNK) chunkSum[t] = s[t] - v;
}

__global__ void k_scan3(int* __restrict__ cursor, const int* __restrict__ chunkSum) {
  int i = blockIdx.x * SCAN_B + threadIdx.x;
  if (i < N_NODES) cursor[i] += chunkSum[blockIdx.x];
}

__global__ void k_scatter_sort(const int* __restrict__ dst, int* __restrict__ cursor,
                               int* __restrict__ sorted) {
  int e = blockIdx.x * blockDim.x + threadIdx.x;
  if (e < N_EDGES) {
    int p = atomicAdd(&cursor[dst[e]], 1);
    sorted[p] = e;
  }
}

// ---------------- fp32 -> bf16 conversions ----------------

__global__ void k_cvt_x(const float* __restrict__ x, unsigned short* __restrict__ xb, int n4) {
  int i = blockIdx.x * blockDim.x + threadIdx.x;
  if (i < n4) {
    float4 v = ((const float4*)x)[i];
    ushort4v o;
    o[0] = f2b(v.x); o[1] = f2b(v.y); o[2] = f2b(v.z); o[3] = f2b(v.w);
    ((ushort4v*)xb)[i] = o;
  }
}

// src [L][K][N] fp32 -> dst [L][N][K] bf16
__global__ void k_cvt_wt(const float* __restrict__ src, unsigned short* __restrict__ dst,
                         int K, int N, int total) {
  int i = blockIdx.x * blockDim.x + threadIdx.x;
  if (i < total) {
    int l = i / (K * N);
    int rem = i - l * K * N;
    int k = rem / N;
    int n = rem - k * N;
    dst[((size_t)l * N + n) * K + k] = f2b(src[i]);
  }
}

// ---------------- MFMA helpers ----------------
// wave wv owns output rows wv*16..+15; 8 N-tiles of 16 cols.
// A fragment: row = wv*16 + (lane&15), k = kbase + ks*32 + quad*8 (8 contiguous bf16)
// B (LDS, [N][K] pitch 72): row n = nt*16 + (lane&15), same k window.
// C/D: D[wv*16 + quad*4 + r][nt*16 + (lane&15)] = acc[nt][r]
#define MFMA_STEP(AP, APITCH, AKOFF, ACCN)                                         \
  { _Pragma("unroll")                                                              \
    for (int ks = 0; ks < 2; ++ks) {                                               \
      short8v af_ = *(const short8v*)&AP[(wv * 16 + ln15) * APITCH + (AKOFF) + ks * 32 + quad * 8]; \
      _Pragma("unroll")                                                            \
      for (int nt = 0; nt < 8; ++nt) {                                             \
        short8v bf_ = *(const short8v*)&sB[(nt * 16 + ln15) * 72 + ks * 32 + quad * 8]; \
        ACCN[nt] = __builtin_amdgcn_mfma_f32_16x16x32_bf16(af_, bf_, ACCN[nt], 0, 0, 0); \
      } } }

// stage one 128xKC(=64) B chunk from a pre-transposed [N][K] bf16 weight matrix
#define STAGE_B(EXPR)                                                              \
  { _Pragma("unroll")                                                              \
    for (int i_ = 0; i_ < 4; ++i_) {                                               \
      int flat_ = tid + i_ * 256;                                                  \
      int n = flat_ >> 3, seg = flat_ & 7;                                         \
      *(float4*)&sB[n * 72 + seg * 8] = *(const float4*)&(EXPR);                   \
    } }

// ---------------- fused edge kernel (bf16 MFMA) ----------------

__launch_bounds__(256, 3)
__global__ void k_edge(const unsigned short* __restrict__ xb,
                       const float* __restrict__ pos,
                       const float* __restrict__ eattr,
                       const int* __restrict__ srcI,
                       const int* __restrict__ dstI,
                       const int* __restrict__ sorted,
                       const unsigned short* __restrict__ mW1t, const float* __restrict__ mb1,
                       const unsigned short* __restrict__ mW2t, const float* __restrict__ mb2,
                       const unsigned short* __restrict__ aW1t, const float* __restrict__ ab1,
                       const float* __restrict__ aW2, const float* __restrict__ ab2,
                       float* __restrict__ intra,
                       float* __restrict__ pdelta,
                       int do_intra)
{
  __shared__ unsigned short sA[64 * 72];    // A chunk [64][64] bf16, pitch 72
  __shared__ unsigned short sB[128 * 72];   // B chunk [128][64] bf16, pitch 72
  __shared__ unsigned short sM[64 * 136];   // h1 then m, [64][128] bf16, pitch 136
  __shared__ int sEid[64], sSrc[64], sDst[64];
  __shared__ float sW[64];
  __shared__ float sPE[64 * 3];

  const int tid = threadIdx.x;
  const int e0 = blockIdx.x * 64;
  const int nv = min(N_EDGES - e0, 64);
  if (tid < 64) {
    int idx = min(e0 + tid, N_EDGES - 1);
    int eid = sorted[idx];
    sEid[tid] = eid; sSrc[tid] = srcI[eid]; sDst[tid] = dstI[eid];
  }
  __syncthreads();

  const int wv = tid >> 6, lane = tid & 63, quad = lane >> 4, ln15 = lane & 15;

  f32x4 acc[8];
#pragma unroll
  for (int nt = 0; nt < 8; ++nt) acc[nt] = (f32x4){0.f, 0.f, 0.f, 0.f};

  // ---- GEMM1: concat(xb[dst], xb[src], eattr) [64][384] @ mW1 -> [64][128]
  for (int c = 0; c < 6; ++c) {
    // stage A chunk (cols c*64 .. c*64+63 of the concat row)
#pragma unroll
    for (int i_ = 0; i_ < 2; ++i_) {
      int flat_ = tid + i_ * 256;
      int row = flat_ >> 3, seg = flat_ & 7;
      if (c < 4) {
        int node = (c < 2) ? sDst[row] : sSrc[row];
        const unsigned short* sp = xb + (size_t)node * H + (c & 1) * 64 + seg * 8;
        *(float4*)&sA[row * 72 + seg * 8] = *(const float4*)sp;
      } else {
        const float* ep = eattr + (size_t)sEid[row] * H + (c - 4) * 64 + seg * 8;
        float4 p0 = *(const float4*)ep;
        float4 p1 = *(const float4*)(ep + 4);
        ushort8v v;
        v[0] = f2b(p0.x); v[1] = f2b(p0.y); v[2] = f2b(p0.z); v[3] = f2b(p0.w);
        v[4] = f2b(p1.x); v[5] = f2b(p1.y); v[6] = f2b(p1.z); v[7] = f2b(p1.w);
        *(ushort8v*)&sA[row * 72 + seg * 8] = v;
      }
    }
    STAGE_B(mW1t[(size_t)n * 384 + c * 64 + seg * 8])
    __syncthreads();
    MFMA_STEP(sA, 72, 0, acc)
    __syncthreads();
  }

  // h1 = relu(acc + mb1) -> sM
#pragma unroll
  for (int nt = 0; nt < 8; ++nt) {
    int col = nt * 16 + ln15;
    float bb = mb1[col];
#pragma unroll
    for (int r = 0; r < 4; ++r) {
      int row = wv * 16 + quad * 4 + r;
      sM[row * 136 + col] = f2b(fmaxf(acc[nt][r] + bb, 0.f));
      acc[nt][r] = 0.f;
    }
  }
  __syncthreads();

  // ---- GEMM2: h1 [64][128] @ mW2 -> m [64][128]
  for (int c = 0; c < 2; ++c) {
    STAGE_B(mW2t[(size_t)n * 128 + c * 64 + seg * 8])
    __syncthreads();
    MFMA_STEP(sM, 136, c * 64, acc)
    __syncthreads();
  }

  // m = acc + mb2 -> sM (all GEMM2 reads done)
#pragma unroll
  for (int nt = 0; nt < 8; ++nt) {
    int col = nt * 16 + ln15;
    float bb = mb2[col];
#pragma unroll
    for (int r = 0; r < 4; ++r) {
      int row = wv * 16 + quad * 4 + r;
      sM[row * 136 + col] = f2b(acc[nt][r] + bb);
    }
  }
  __syncthreads();

  // ---- acc MLP: w = relu(m @ aW1 + ab1) @ aW2 + ab2
  float wp0 = 0.f, wp1 = 0.f, wp2 = 0.f, wp3 = 0.f;
  for (int h = 0; h < 2; ++h) {
#pragma unroll
    for (int nt = 0; nt < 8; ++nt) acc[nt] = (f32x4){0.f, 0.f, 0.f, 0.f};
    for (int c = 0; c < 2; ++c) {
      STAGE_B(aW1t[((size_t)h * 128 + n) * 128 + c * 64 + seg * 8])
      __syncthreads();
      MFMA_STEP(sM, 136, c * 64, acc)
      __syncthreads();
    }
#pragma unroll
    for (int nt = 0; nt < 8; ++nt) {
      int col = h * 128 + nt * 16 + ln15;
      float bb = ab1[col], a2 = aW2[col];
      wp0 += fmaxf(acc[nt][0] + bb, 0.f) * a2;
      wp1 += fmaxf(acc[nt][1] + bb, 0.f) * a2;
      wp2 += fmaxf(acc[nt][2] + bb, 0.f) * a2;
      wp3 += fmaxf(acc[nt][3] + bb, 0.f) * a2;
    }
  }
  // reduce across the 16 lanes of each quad (cols)
#pragma unroll
  for (int m = 1; m <= 8; m <<= 1) {
    wp0 += __shfl_xor(wp0, m, 64);
    wp1 += __shfl_xor(wp1, m, 64);
    wp2 += __shfl_xor(wp2, m, 64);
    wp3 += __shfl_xor(wp3, m, 64);
  }
  if (ln15 == 0) {
    float b2 = ab2[0];
    sW[wv * 16 + quad * 4 + 0] = wp0 + b2;
    sW[wv * 16 + quad * 4 + 1] = wp1 + b2;
    sW[wv * 16 + quad * 4 + 2] = wp2 + b2;
    sW[wv * 16 + quad * 4 + 3] = wp3 + b2;
  }
  __syncthreads();

  // ---- per-edge acc_e into LDS ----
  if (tid < nv) {
    int s = sSrc[tid], d = sDst[tid];
    float rx = pos[s * 3 + 0] - pos[d * 3 + 0];
    float ry = pos[s * 3 + 1] - pos[d * 3 + 1];
    float rz = pos[s * 3 + 2] - pos[d * 3 + 2];
    float dist = sqrtf(rx * rx + ry * ry + rz * rz);
    float cf = sW[tid] / dist;
    sPE[tid * 3 + 0] = cf * rx;
    sPE[tid * 3 + 1] = cf * ry;
    sPE[tid * 3 + 2] = cf * rz;
  }
  __syncthreads();

  // ---- segment-reduced scatter: pdelta (dst-sorted tiles) ----
  if (tid < 3) {
    float run = 0.0f;
    int cur = -2;
    for (int e = 0; e < 64; ++e) {
      int d = (e < nv) ? sDst[e] : -1;
      if (d != cur) {
        if (cur >= 0 && run != 0.0f) atomicAdd(&pdelta[cur * 3 + tid], run);
        run = 0.0f;
        cur = d;
      }
      if (d >= 0) run += sPE[e * 3 + tid];
    }
    if (cur >= 0 && run != 0.0f) atomicAdd(&pdelta[cur * 3 + tid], run);
  }

  // ---- segment-reduced scatter: intra (m is bf16 in sM) ----
  if (do_intra) {
    int f = tid & 127;
    int hf = tid >> 7;
    int eBeg = hf * 32, eEnd = eBeg + 32;
    float run = 0.0f;
    int cur = -2;
    for (int e = eBeg; e < eEnd; ++e) {
      int d = (e < nv) ? sDst[e] : -1;
      if (d != cur) {
        if (cur >= 0 && run != 0.0f) atomicAdd(&intra[(size_t)cur * H + f], run);
        run = 0.0f;
        cur = d;
      }
      if (d >= 0) run += b2f(sM[e * 136 + f]);
    }
    if (cur >= 0 && run != 0.0f) atomicAdd(&intra[(size_t)cur * H + f], run);
  }
}

// ---------------- node kernel (bf16 MFMA) ----------------

__launch_bounds__(256, 3)
__global__ void k_node(const unsigned short* __restrict__ xb,
                       const float* __restrict__ intra,
                       const float* __restrict__ invd,
                       const unsigned short* __restrict__ nW1t, const float* __restrict__ nb1,
                       const unsigned short* __restrict__ nW2t, const float* __restrict__ nb2,
                       const float* __restrict__ pos_in,
                       const float* __restrict__ pdelta,
                       unsigned short* __restrict__ xb_out,
                       float* __restrict__ pos_out,
                       int compute_x)
{
  __shared__ unsigned short sA[64 * 72];
  __shared__ unsigned short sB[128 * 72];
  __shared__ unsigned short sH[64 * 136];
  const int tid = threadIdx.x;
  const int n0 = blockIdx.x * 64;

  if (tid < 192) {
    int n = n0 + tid / 3, cc = tid % 3;
    if (n < N_NODES)
      pos_out[n * 3 + cc] = pos_in[n * 3 + cc] + pdelta[n * 3 + cc] * invd[n];
  }
  if (!compute_x) return;

  const int wv = tid >> 6, lane = tid & 63, quad = lane >> 4, ln15 = lane & 15;

  f32x4 xacc[8];
#pragma unroll
  for (int nt = 0; nt < 8; ++nt) xacc[nt] = (f32x4){0.f, 0.f, 0.f, 0.f};

  f32x4 acc[8];
  for (int h = 0; h < 2; ++h) {
#pragma unroll
    for (int nt = 0; nt < 8; ++nt) acc[nt] = (f32x4){0.f, 0.f, 0.f, 0.f};
    // GEMM-A: concat(xb, intra*invd) [64][256] @ nW1[:, h*128..] -> h-half
    for (int c = 0; c < 4; ++c) {
#pragma unroll
      for (int i_ = 0; i_ < 2; ++i_) {
        int flat_ = tid + i_ * 256;
        int row = flat_ >> 3, seg = flat_ & 7;
        int n = min(n0 + row, N_NODES - 1);
        if (c < 2) {
          *(float4*)&sA[row * 72 + seg * 8] =
              *(const float4*)&xb[(size_t)n * H + c * 64 + seg * 8];
        } else {
          const float* ip = intra + (size_t)n * H + (c - 2) * 64 + seg * 8;
          float iv = invd[n];
          float4 p0 = *(const float4*)ip;
          float4 p1 = *(const float4*)(ip + 4);
          ushort8v v;
          v[0] = f2b(p0.x * iv); v[1] = f2b(p0.y * iv);
          v[2] = f2b(p0.z * iv); v[3] = f2b(p0.w * iv);
          v[4] = f2b(p1.x * iv); v[5] = f2b(p1.y * iv);
          v[6] = f2b(p1.z * iv); v[7] = f2b(p1.w * iv);
          *(ushort8v*)&sA[row * 72 + seg * 8] = v;
        }
      }
      STAGE_B(nW1t[((size_t)h * 128 + n) * 256 + c * 64 + seg * 8])
      __syncthreads();
      MFMA_STEP(sA, 72, 0, acc)
      __syncthreads();
    }
    // h-half = relu(acc + nb1) -> sH
#pragma unroll
    for (int nt = 0; nt < 8; ++nt) {
      int col = nt * 16 + ln15;
      float bb = nb1[h * 128 + col];
#pragma unroll
      for (int r = 0; r < 4; ++r) {
        int row = wv * 16 + quad * 4 + r;
        sH[row * 136 + col] = f2b(fmaxf(acc[nt][r] + bb, 0.f));
      }
    }
    __syncthreads();
    // GEMM-B partial: sH [64][128] @ nW2[h*128.., :] into xacc
    for (int c2 = 0; c2 < 2; ++c2) {
      STAGE_B(nW2t[(size_t)n * 256 + h * 128 + c2 * 64 + seg * 8])
      __syncthreads();
      MFMA_STEP(sH, 136, c2 * 64, xacc)
      __syncthreads();
    }
  }
  // x_out = xacc + nb2 (bf16)
#pragma unroll
  for (int nt = 0; nt < 8; ++nt) {
    int col = nt * 16 + ln15;
    float bb = nb2[col];
#pragma unroll
    for (int r = 0; r < 4; ++r) {
      int row = n0 + wv * 16 + quad * 4 + r;
      if (row < N_NODES)
        xb_out[(size_t)row * H + col] = f2b(xacc[nt][r] + bb);
    }
  }
}

extern "C" void kernel_launch(void* const* d_in, const int* in_sizes, int n_in,
                              void* d_out, int out_size, void* d_ws, size_t ws_size,
                              hipStream_t stream) {
  const float* x0    = (const float*)d_in[0];
  const int*   eidx  = (const int*)d_in[1];
  const float* eattr = (const float*)d_in[2];
  const float* pos0  = (const float*)d_in[3];
  const float* mW1 = (const float*)d_in[4];
  const float* mb1 = (const float*)d_in[5];
  const float* mW2 = (const float*)d_in[6];
  const float* mb2 = (const float*)d_in[7];
  const float* aW1 = (const float*)d_in[8];
  const float* ab1 = (const float*)d_in[9];
  const float* aW2 = (const float*)d_in[10];
  const float* ab2 = (const float*)d_in[11];
  const float* nW1 = (const float*)d_in[12];
  const float* nb1 = (const float*)d_in[13];
  const float* nW2 = (const float*)d_in[14];
  const float* nb2 = (const float*)d_in[15];
  const int* srcI = eidx;
  const int* dstI = eidx + N_EDGES;

  char* wsb = (char*)d_ws;
  int*   degC    = (int*)wsb;                     wsb += (size_t)N_NODES * 4;
  int*   cursor  = (int*)wsb;                     wsb += (size_t)N_NODES * 4;
  int*   chunkS  = (int*)wsb;                     wsb += 256 * 4;
  int*   sorted  = (int*)wsb;                     wsb += (size_t)N_EDGES * 4;
  float* invd    = (float*)wsb;                   wsb += (size_t)N_NODES * 4;
  float* pdelta  = (float*)wsb;                   wsb += (size_t)3 * N_NODES * 4;
  float* pos_a   = (float*)wsb;                   wsb += (size_t)3 * N_NODES * 4;
  float* pos_b   = (float*)wsb;                   wsb += (size_t)3 * N_NODES * 4;
  float* intra   = (float*)wsb;                   wsb += (size_t)N_NODES * H * 4;
  unsigned short* xb0  = (unsigned short*)wsb;    wsb += (size_t)N_NODES * H * 2;
  unsigned short* xb_a = (unsigned short*)wsb;    wsb += (size_t)N_NODES * H * 2;
  unsigned short* xb_b = (unsigned short*)wsb;    wsb += (size_t)N_NODES * H * 2;
  unsigned short* mW1t = (unsigned short*)wsb;    wsb += (size_t)NL * 128 * 384 * 2;
  unsigned short* mW2t = (unsigned short*)wsb;    wsb += (size_t)NL * 128 * 128 * 2;
  unsigned short* aW1t = (unsigned short*)wsb;    wsb += (size_t)NL * 256 * 128 * 2;
  unsigned short* nW1t = (unsigned short*)wsb;    wsb += (size_t)NL * 256 * 256 * 2;
  unsigned short* nW2t = (unsigned short*)wsb;    wsb += (size_t)NL * 128 * 256 * 2;

  // counting sort of edges by dst (every launch; ws is re-poisoned)
  hipMemsetAsync(degC, 0, N_NODES * sizeof(int), stream);
  k_deg_i<<<(N_EDGES + 255) / 256, 256, 0, stream>>>(dstI, degC);
  k_inv<<<(N_NODES + 255) / 256, 256, 0, stream>>>(degC, invd);
  k_scan1<<<NCHUNK, SCAN_B, 0, stream>>>(degC, cursor, chunkS);
  k_scan2<<<1, SCAN_B, 0, stream>>>(chunkS);
  k_scan3<<<NCHUNK, SCAN_B, 0, stream>>>(cursor, chunkS);
  k_scatter_sort<<<(N_EDGES + 255) / 256, 256, 0, stream>>>(dstI, cursor, sorted);

  // bf16 conversions
  {
    int n4 = N_NODES * H / 4;
    k_cvt_x<<<(n4 + 255) / 256, 256, 0, stream>>>(x0, xb0, n4);
    int t1 = NL * 384 * 128;
    k_cvt_wt<<<(t1 + 255) / 256, 256, 0, stream>>>(mW1, mW1t, 384, 128, t1);
    int t2 = NL * 128 * 128;
    k_cvt_wt<<<(t2 + 255) / 256, 256, 0, stream>>>(mW2, mW2t, 128, 128, t2);
    int t3 = NL * 128 * 256;
    k_cvt_wt<<<(t3 + 255) / 256, 256, 0, stream>>>(aW1, aW1t, 128, 256, t3);
    int t4 = NL * 256 * 256;
    k_cvt_wt<<<(t4 + 255) / 256, 256, 0, stream>>>(nW1, nW1t, 256, 256, t4);
    int t5 = NL * 256 * 128;
    k_cvt_wt<<<(t5 + 255) / 256, 256, 0, stream>>>(nW2, nW2t, 256, 128, t5);
  }

  const unsigned short* xc = xb0;
  const float* pc = pos0;
  float* pos_out_final = (float*)d_out;

  for (int l = 0; l < NL; ++l) {
    int last = (l == NL - 1);
    hipMemsetAsync(pdelta, 0, 3 * N_NODES * sizeof(float), stream);
    if (!last)
      hipMemsetAsync(intra, 0, (size_t)N_NODES * H * sizeof(float), stream);

    k_edge<<<(N_EDGES + 63) / 64, 256, 0, stream>>>(
        xc, pc, eattr, srcI, dstI, sorted,
        mW1t + (size_t)l * 128 * 384, mb1 + (size_t)l * 128,
        mW2t + (size_t)l * 128 * 128, mb2 + (size_t)l * 128,
        aW1t + (size_t)l * 256 * 128, ab1 + (size_t)l * 256,
        aW2 + (size_t)l * 256, ab2 + l,
        intra, pdelta, last ? 0 : 1);

    float* pn = last ? pos_out_final : (l == 0 ? pos_a : pos_b);
    unsigned short* xn = (l == 0) ? xb_a : xb_b;
    k_node<<<(N_NODES + 63) / 64, 256, 0, stream>>>(
        xc, intra, invd,
        nW1t + (size_t)l * 256 * 256, nb1 + (size_t)l * 256,
        nW2t + (size_t)l * 128 * 256, nb2 + (size_t)l * 128,
        pc, pdelta, xn, pn, last ? 0 : 1);

    xc = xn;
    pc = pn;
  }
}